// Round 4
// baseline (206.158 us; speedup 1.0000x reference)
//
#include <hip/hip_runtime.h>
#include <cmath>

#define NDEV   100000
#define NBATCH 8192
#define CONTF  62
#define EMB    16
#define FEAT   94      // 62 + 16 + 16
#define KNBR   64
#define NH     4
#define OUTD   16
#define HOUT   64      // NH*OUTD
#define FUS    204     // 94 + 94 + 16
#define ALPHA  0.2f

#define NDEVW  1563    // ceil(100000/64) device waves
#define NCOMBW 128     // 8192/64 comb waves

// ---------------- workspace layout (floats) ----------------
// h_d : NDEV*64    = 6,400,000 @ 0
// e_d : NDEV*4     =   400,000 @ 6,400,000
// e_c : NBATCH*4   =    32,768 @ 6,800,000
// fus : NBATCH*204 = 1,671,168 @ 6,832,768   (row-major [b][204])

template <typename T>
__device__ __forceinline__ const T* uniform_ptr(const T* p) {
  uint64_t v = (uint64_t)(uintptr_t)p;
  uint32_t lo = __builtin_amdgcn_readfirstlane((uint32_t)v);
  uint32_t hi = __builtin_amdgcn_readfirstlane((uint32_t)(v >> 32));
  return (const T*)(uintptr_t)(((uint64_t)hi << 32) | lo);
}

// one feature's 64 FMAs; Wl is an SGPR pointer, f wave-uniform -> s_load feed
__device__ __forceinline__ void fma_feat(float acc[HOUT], float x,
                                         const float* __restrict__ Wl, int f) {
#pragma unroll
  for (int j = 0; j < HOUT; ++j)
    acc[j] = fmaf(x, Wl[f * HOUT + j], acc[j]);
}

// ---------------- K1: X[row,94] @ W[94,64], lane = row, no LDS ----------------
__global__ __launch_bounds__(64) void k_feat(
    const float* __restrict__ device_cont, const int* __restrict__ device_cat,
    const float* __restrict__ de0, const float* __restrict__ de1,
    const float* __restrict__ Wd, const float* __restrict__ bd,
    const float* __restrict__ combin_cont, const int* __restrict__ combin_cat,
    const int* __restrict__ combin_idx,
    const float* __restrict__ ce0, const float* __restrict__ ce1,
    const float* __restrict__ Wc, const float* __restrict__ bc,
    const float* __restrict__ aW,
    float* __restrict__ h_d, float* __restrict__ e_d, float* __restrict__ e_c) {
  const int lane = threadIdx.x;
  const int w = blockIdx.x;
  const bool devp = w < NDEVW;

  const int row = devp ? w * 64 + lane : (w - NDEVW) * 64 + lane;
  const bool valid = devp ? (row < NDEV) : true;
  const int r = valid ? row : NDEV - 1;

  const int src = devp ? r : combin_idx[r];
  const int2 cat = reinterpret_cast<const int2*>(devp ? device_cat : combin_cat)[src];
  const float* __restrict__ crow =
      (devp ? device_cont : combin_cont) + (size_t)src * CONTF;
  const float* __restrict__ e0p = (devp ? de0 : ce0) + (size_t)cat.x * EMB;
  const float* __restrict__ e1p = (devp ? de1 : ce1) + (size_t)cat.y * EMB;

  // wave-uniform scalar pointers (force SGPR so W/bias feed via s_load)
  const float* Wl   = uniform_ptr(devp ? Wd : Wc);
  const float* bl   = uniform_ptr(devp ? bd : bc);
  const float* aWl  = uniform_ptr(aW) + (devp ? OUTD : 0);

  float acc[HOUT];
#pragma unroll
  for (int j = 0; j < HOUT; ++j) acc[j] = bl[j];

  // ---- continuous features 0..55 in chunks of 8 (looped: I-cache) ----
#pragma unroll 1
  for (int c7 = 0; c7 < 7; ++c7) {
    const float2* p = reinterpret_cast<const float2*>(crow + c7 * 8);
    const float2 a0 = p[0], a1 = p[1], a2 = p[2], a3 = p[3];
    const float xs[8] = {a0.x, a0.y, a1.x, a1.y, a2.x, a2.y, a3.x, a3.y};
#pragma unroll
    for (int c = 0; c < 8; ++c) fma_feat(acc, xs[c], Wl, c7 * 8 + c);
  }
  // ---- tail 56..61 ----
  {
    const float2* p = reinterpret_cast<const float2*>(crow + 56);
    const float2 a0 = p[0], a1 = p[1], a2 = p[2];
    const float xs[6] = {a0.x, a0.y, a1.x, a1.y, a2.x, a2.y};
#pragma unroll
    for (int c = 0; c < 6; ++c) fma_feat(acc, xs[c], Wl, 56 + c);
  }
  // ---- embedding 0: features 62..77 ----
#pragma unroll 1
  for (int t = 0; t < 2; ++t) {
    const float4 a0 = reinterpret_cast<const float4*>(e0p)[2 * t];
    const float4 a1 = reinterpret_cast<const float4*>(e0p)[2 * t + 1];
    const float xs[8] = {a0.x, a0.y, a0.z, a0.w, a1.x, a1.y, a1.z, a1.w};
#pragma unroll
    for (int c = 0; c < 8; ++c) fma_feat(acc, xs[c], Wl, CONTF + t * 8 + c);
  }
  // ---- embedding 1: features 78..93 ----
#pragma unroll 1
  for (int t = 0; t < 2; ++t) {
    const float4 a0 = reinterpret_cast<const float4*>(e1p)[2 * t];
    const float4 a1 = reinterpret_cast<const float4*>(e1p)[2 * t + 1];
    const float xs[8] = {a0.x, a0.y, a0.z, a0.w, a1.x, a1.y, a1.z, a1.w};
#pragma unroll
    for (int c = 0; c < 8; ++c) fma_feat(acc, xs[c], Wl, CONTF + EMB + t * 8 + c);
  }

  // ---- epilogue: attention logits e[h] = sum_o acc[h*16+o]*aW[h][aoff+o] ----
  float ev[NH];
#pragma unroll
  for (int h = 0; h < NH; ++h) {
    float s = 0.f;
#pragma unroll
    for (int o = 0; o < OUTD; ++o)
      s = fmaf(acc[h * OUTD + o], aWl[h * 2 * OUTD + o], s);
    ev[h] = s;
  }

  if (devp) {
    if (valid) {
      float4* hrow = reinterpret_cast<float4*>(h_d + (size_t)row * HOUT);
#pragma unroll
      for (int t = 0; t < 16; ++t)
        hrow[t] = make_float4(acc[4 * t], acc[4 * t + 1], acc[4 * t + 2], acc[4 * t + 3]);
      reinterpret_cast<float4*>(e_d)[row] = make_float4(ev[0], ev[1], ev[2], ev[3]);
    }
  } else {
    reinterpret_cast<float4*>(e_c)[row] = make_float4(ev[0], ev[1], ev[2], ev[3]);
  }
}

// ---------------- K2: attention + fusion-row build ----------------
__global__ __launch_bounds__(256, 4) void k_attn(
    const int* __restrict__ neighbor_idx, const int* __restrict__ device_idx,
    const int* __restrict__ device_cat, const float* __restrict__ device_cont,
    const float* __restrict__ de0, const float* __restrict__ de1,
    const int* __restrict__ combin_idx, const int* __restrict__ combin_cat,
    const float* __restrict__ combin_cont,
    const float* __restrict__ ce0, const float* __restrict__ ce1,
    const float* __restrict__ h_d, const float* __restrict__ e_d,
    const float* __restrict__ e_c, const float* __restrict__ ab,
    const float* __restrict__ W1, const float* __restrict__ b1,
    float* __restrict__ fus) {
  __shared__ __align__(16) float pb[4][NH][68];
  __shared__ __align__(16) int   nb[4][KNBR];
  __shared__ float hb[4][HOUT];
  __shared__ float afb[4][OUTD];

  const int lane = threadIdx.x & 63;
  const int wid  = __builtin_amdgcn_readfirstlane((int)(threadIdx.x >> 6));
  const int b    = blockIdx.x * 4 + wid;

  // ---- phase 1: lane = neighbor k ----
  const int nk = neighbor_idx[(size_t)b * KNBR + lane];
  const float4 ed4 = *reinterpret_cast<const float4*>(e_d + (size_t)nk * NH);
  const float4 ec4 = *reinterpret_cast<const float4*>(e_c + (size_t)b * NH);
  const float4 ab4 = *reinterpret_cast<const float4*>(ab);

  float v0 = ec4.x + ed4.x + ab4.x;
  float v1 = ec4.y + ed4.y + ab4.y;
  float v2 = ec4.z + ed4.z + ab4.z;
  float v3 = ec4.w + ed4.w + ab4.w;
  v0 = v0 > 0.f ? v0 : ALPHA * v0;
  v1 = v1 > 0.f ? v1 : ALPHA * v1;
  v2 = v2 > 0.f ? v2 : ALPHA * v2;
  v3 = v3 > 0.f ? v3 : ALPHA * v3;

  float m0 = v0, m1 = v1, m2 = v2, m3 = v3;
#pragma unroll
  for (int msk = 1; msk < 64; msk <<= 1) {
    m0 = fmaxf(m0, __shfl_xor(m0, msk));
    m1 = fmaxf(m1, __shfl_xor(m1, msk));
    m2 = fmaxf(m2, __shfl_xor(m2, msk));
    m3 = fmaxf(m3, __shfl_xor(m3, msk));
  }
  float p0 = expf(v0 - m0), p1 = expf(v1 - m1), p2 = expf(v2 - m2), p3 = expf(v3 - m3);
  float s0 = p0, s1 = p1, s2 = p2, s3 = p3;
#pragma unroll
  for (int msk = 1; msk < 64; msk <<= 1) {
    s0 += __shfl_xor(s0, msk);
    s1 += __shfl_xor(s1, msk);
    s2 += __shfl_xor(s2, msk);
    s3 += __shfl_xor(s3, msk);
  }
  p0 /= s0; p1 /= s1; p2 /= s2; p3 /= s3;

  pb[wid][0][lane] = p0;
  pb[wid][1][lane] = p1;
  pb[wid][2][lane] = p2;
  pb[wid][3][lane] = p3;
  nb[wid][lane]    = nk;
  __syncthreads();

  // ---- phase 2: lane = (h,o), gather h_d ----
  const int h = lane >> 4;
  float acc = 0.f;
#pragma unroll
  for (int j = 0; j < 16; ++j) {
    const float4 p4 = *reinterpret_cast<const float4*>(&pb[wid][h][4 * j]);
    const int4   n4 = *reinterpret_cast<const int4*>(&nb[wid][4 * j]);
    acc = fmaf(p4.x, h_d[(size_t)n4.x * HOUT + lane], acc);
    acc = fmaf(p4.y, h_d[(size_t)n4.y * HOUT + lane], acc);
    acc = fmaf(p4.z, h_d[(size_t)n4.z * HOUT + lane], acc);
    acc = fmaf(p4.w, h_d[(size_t)n4.w * HOUT + lane], acc);
  }
  const float ho = acc > 0.f ? acc : expm1f(acc);  // elu
  hb[wid][lane] = ho;
  __syncthreads();

  // ---- attn_feats = head_out(64) @ W1(64x16) + b1 ----
  {
    const int j = lane & 15, g = lane >> 4;
    float part = 0.f;
#pragma unroll
    for (int t = 0; t < 16; ++t)
      part = fmaf(hb[wid][g * 16 + t], W1[(g * 16 + t) * OUTD + j], part);
    part += __shfl_xor(part, 16);
    part += __shfl_xor(part, 32);
    if (lane < 16) afb[wid][lane] = part + b1[lane];
  }
  __syncthreads();

  // ---- fusion row [comb 94 | dev 94 | att 16], row-major coalesced ----
  const int ci = combin_idx[b];
  const int cc0 = combin_cat[2 * ci], cc1 = combin_cat[2 * ci + 1];
  const int didx = device_idx[b];
  const int dc0 = device_cat[2 * didx], dc1 = device_cat[2 * didx + 1];
  float* __restrict__ frow = fus + (size_t)b * FUS;
#pragma unroll
  for (int t = 0; t < 4; ++t) {
    const int i = lane + t * 64;
    if (i < FUS) {
      float v;
      if (i < 62)       v = combin_cont[(size_t)ci * CONTF + i];
      else if (i < 78)  v = ce0[(size_t)cc0 * EMB + (i - 62)];
      else if (i < 94)  v = ce1[(size_t)cc1 * EMB + (i - 78)];
      else if (i < 156) v = device_cont[(size_t)didx * CONTF + (i - 94)];
      else if (i < 172) v = de0[(size_t)dc0 * EMB + (i - 156)];
      else if (i < 188) v = de1[(size_t)dc1 * EMB + (i - 172)];
      else              v = afb[wid][i - 188];
      frow[i] = v;
    }
  }
}

// ---------------- K3: MLP (204 -> 64 -> 32 -> 1), 4 rows per wave ----------------
__global__ __launch_bounds__(256) void k_mlp(
    const float* __restrict__ fus,
    const float* __restrict__ W2, const float* __restrict__ b2,
    const float* __restrict__ W3, const float* __restrict__ b3,
    const float* __restrict__ W4, const float* __restrict__ b4,
    float* __restrict__ out) {
  __shared__ __align__(16) float x1w[4][4][64];
  const int lane = threadIdx.x & 63;
  const int wid  = __builtin_amdgcn_readfirstlane((int)(threadIdx.x >> 6));
  const int w    = blockIdx.x * 4 + wid;
  const int r0   = w * 4;  // 4 rows per wave

  const float* rp0 = uniform_ptr(fus + (size_t)(r0 + 0) * FUS);
  const float* rp1 = uniform_ptr(fus + (size_t)(r0 + 1) * FUS);
  const float* rp2 = uniform_ptr(fus + (size_t)(r0 + 2) * FUS);
  const float* rp3 = uniform_ptr(fus + (size_t)(r0 + 3) * FUS);

  float acc[4];
  const float bj = b2[lane];
#pragma unroll
  for (int r = 0; r < 4; ++r) acc[r] = bj;

  // layer 1: x1[r][lane] = relu(fus[r] . W2[:,lane])
#pragma unroll 1
  for (int c = 0; c < 25; ++c) {  // 25*8 = 200
    const int f0 = c * 8;
#pragma unroll
    for (int k = 0; k < 8; ++k) {
      const float wv = W2[(f0 + k) * 64 + lane];
      acc[0] = fmaf(rp0[f0 + k], wv, acc[0]);
      acc[1] = fmaf(rp1[f0 + k], wv, acc[1]);
      acc[2] = fmaf(rp2[f0 + k], wv, acc[2]);
      acc[3] = fmaf(rp3[f0 + k], wv, acc[3]);
    }
  }
#pragma unroll
  for (int k = 0; k < 4; ++k) {  // tail 200..203
    const float wv = W2[(200 + k) * 64 + lane];
    acc[0] = fmaf(rp0[200 + k], wv, acc[0]);
    acc[1] = fmaf(rp1[200 + k], wv, acc[1]);
    acc[2] = fmaf(rp2[200 + k], wv, acc[2]);
    acc[3] = fmaf(rp3[200 + k], wv, acc[3]);
  }
#pragma unroll
  for (int r = 0; r < 4; ++r) x1w[wid][r][lane] = fmaxf(acc[r], 0.f);
  // wave-local LDS round-trip; compiler inserts lgkmcnt wait, no barrier needed

  // layer 2: lanes 0-31 rows {0,1}, lanes 32-63 rows {2,3}; m = output col
  const int m = lane & 31, rh = lane >> 5;
  float x2[2];
#pragma unroll
  for (int r = 0; r < 2; ++r) x2[r] = b3[m];
#pragma unroll 2
  for (int j4 = 0; j4 < 16; ++j4) {
    const float w30 = W3[(4 * j4 + 0) * 32 + m];
    const float w31 = W3[(4 * j4 + 1) * 32 + m];
    const float w32 = W3[(4 * j4 + 2) * 32 + m];
    const float w33 = W3[(4 * j4 + 3) * 32 + m];
#pragma unroll
    for (int r = 0; r < 2; ++r) {
      const float4 xv = *reinterpret_cast<const float4*>(&x1w[wid][rh * 2 + r][4 * j4]);
      x2[r] = fmaf(xv.x, w30, x2[r]);
      x2[r] = fmaf(xv.y, w31, x2[r]);
      x2[r] = fmaf(xv.z, w32, x2[r]);
      x2[r] = fmaf(xv.w, w33, x2[r]);
    }
  }
  // layer 3 + sigmoid
  const float w4 = W4[m];
  float part[2];
#pragma unroll
  for (int r = 0; r < 2; ++r) part[r] = fmaxf(x2[r], 0.f) * w4;
#pragma unroll
  for (int msk = 1; msk < 32; msk <<= 1) {
#pragma unroll
    for (int r = 0; r < 2; ++r) part[r] += __shfl_xor(part[r], msk);
  }
  if (m == 0) {
    const float bb = b4[0];
#pragma unroll
    for (int r = 0; r < 2; ++r) {
      const float z = part[r] + bb;
      out[(size_t)(r0 + rh * 2 + r)] = 1.f / (1.f + expf(-z));
    }
  }
}

extern "C" void kernel_launch(void* const* d_in, const int* in_sizes, int n_in,
                              void* d_out, int out_size, void* d_ws, size_t ws_size,
                              hipStream_t stream) {
  const float* combin_cont  = (const float*)d_in[0];
  const int*   combin_cat   = (const int*)d_in[1];
  const float* device_cont  = (const float*)d_in[2];
  const int*   device_cat   = (const int*)d_in[3];
  const int*   combin_idx   = (const int*)d_in[4];
  const int*   device_idx   = (const int*)d_in[5];
  const int*   neighbor_idx = (const int*)d_in[6];
  const float* ce0 = (const float*)d_in[7];
  const float* ce1 = (const float*)d_in[8];
  const float* de0 = (const float*)d_in[9];
  const float* de1 = (const float*)d_in[10];
  const float* Wc  = (const float*)d_in[11];
  const float* bc  = (const float*)d_in[12];
  const float* Wd  = (const float*)d_in[13];
  const float* bd  = (const float*)d_in[14];
  const float* aW  = (const float*)d_in[15];
  const float* ab  = (const float*)d_in[16];
  const float* W1  = (const float*)d_in[17];
  const float* b1  = (const float*)d_in[18];
  const float* W2  = (const float*)d_in[19];
  const float* b2  = (const float*)d_in[20];
  const float* W3  = (const float*)d_in[21];
  const float* b3  = (const float*)d_in[22];
  const float* W4  = (const float*)d_in[23];
  const float* b4  = (const float*)d_in[24];

  float* ws  = (float*)d_ws;
  float* h_d = ws;
  float* e_d = ws + 6400000;
  float* e_c = ws + 6800000;
  float* fus = ws + 6832768;

  k_feat<<<NDEVW + NCOMBW, 64, 0, stream>>>(
      device_cont, device_cat, de0, de1, Wd, bd,
      combin_cont, combin_cat, combin_idx, ce0, ce1, Wc, bc, aW,
      h_d, e_d, e_c);
  k_attn<<<2048, 256, 0, stream>>>(
      neighbor_idx, device_idx, device_cat, device_cont, de0, de1,
      combin_idx, combin_cat, combin_cont, ce0, ce1,
      h_d, e_d, e_c, ab, W1, b1, fus);
  k_mlp<<<512, 256, 0, stream>>>(fus, W2, b2, W3, b3, W4, b4, (float*)d_out);
}

// Round 5
// 191.065 us; speedup vs baseline: 1.0790x; 1.0790x over previous
//
#include <hip/hip_runtime.h>
#include <cmath>

#define NDEV   100000
#define NBATCH 8192
#define CONTF  62
#define EMB    16
#define FEAT   94      // 62 + 16 + 16
#define KNBR   64
#define NH     4
#define OUTD   16
#define HOUT   64      // NH*OUTD
#define FUS    204     // 94 + 94 + 16
#define ALPHA  0.2f

#define NDEVG  1563    // ceil(100000/64) row-groups
#define NCOMBG 128     // 8192/64 row-groups

// ---------------- workspace layout (floats) ----------------
// h_d : NDEV*64    = 6,400,000 @ 0
// e_d : NDEV*4     =   400,000 @ 6,400,000
// e_c : NBATCH*4   =    32,768 @ 6,800,000
// fus : NBATCH*204 = 1,671,168 @ 6,832,768   (row-major [b][204])

template <typename T>
__device__ __forceinline__ const T* uniform_ptr(const T* p) {
  uint64_t v = (uint64_t)(uintptr_t)p;
  uint32_t lo = __builtin_amdgcn_readfirstlane((uint32_t)v);
  uint32_t hi = __builtin_amdgcn_readfirstlane((uint32_t)(v >> 32));
  return (const T*)(uintptr_t)(((uint64_t)hi << 32) | lo);
}

// 16 FMAs for one feature; Wg points at this head's [f][16] slab (uniform
// address -> s_load_dwordx16 feed on the scalar pipe, 1 SGPR operand/FMA).
__device__ __forceinline__ void fma16(float acc[OUTD], float x,
                                      const float* __restrict__ Wg, int f) {
  const float4* wr = reinterpret_cast<const float4*>(Wg + f * OUTD);
  const float4 w0 = wr[0], w1 = wr[1], w2 = wr[2], w3 = wr[3];
  acc[0]  = fmaf(x, w0.x, acc[0]);  acc[1]  = fmaf(x, w0.y, acc[1]);
  acc[2]  = fmaf(x, w0.z, acc[2]);  acc[3]  = fmaf(x, w0.w, acc[3]);
  acc[4]  = fmaf(x, w1.x, acc[4]);  acc[5]  = fmaf(x, w1.y, acc[5]);
  acc[6]  = fmaf(x, w1.z, acc[6]);  acc[7]  = fmaf(x, w1.w, acc[7]);
  acc[8]  = fmaf(x, w2.x, acc[8]);  acc[9]  = fmaf(x, w2.y, acc[9]);
  acc[10] = fmaf(x, w2.z, acc[10]); acc[11] = fmaf(x, w2.w, acc[11]);
  acc[12] = fmaf(x, w3.x, acc[12]); acc[13] = fmaf(x, w3.y, acc[13]);
  acc[14] = fmaf(x, w3.z, acc[14]); acc[15] = fmaf(x, w3.w, acc[15]);
}

// ---------------- K1: X[row,94] @ W[94,64], wave = (64 rows, 1 head) ---------
__global__ __launch_bounds__(256, 4) void k_feat(
    const float* __restrict__ device_cont, const int* __restrict__ device_cat,
    const float* __restrict__ de0, const float* __restrict__ de1,
    const float* __restrict__ Wd, const float* __restrict__ bd,
    const float* __restrict__ combin_cont, const int* __restrict__ combin_cat,
    const int* __restrict__ combin_idx,
    const float* __restrict__ ce0, const float* __restrict__ ce1,
    const float* __restrict__ Wc, const float* __restrict__ bc,
    const float* __restrict__ aW,
    float* __restrict__ h_d, float* __restrict__ e_d, float* __restrict__ e_c) {
  const int lane = threadIdx.x & 63;
  const int g = __builtin_amdgcn_readfirstlane((int)(threadIdx.x >> 6));  // head
  const int blk = blockIdx.x;
  const bool devp = blk < NDEVG;

  const int row = (devp ? blk : blk - NDEVG) * 64 + lane;
  const bool valid = devp ? (row < NDEV) : true;
  const int rr = valid ? row : NDEV - 1;

  const int src = devp ? rr : combin_idx[rr];
  const int2 cat = reinterpret_cast<const int2*>(devp ? device_cat : combin_cat)[src];
  const float* __restrict__ crow =
      (devp ? device_cont : combin_cont) + (size_t)src * CONTF;
  const float* __restrict__ e0p = (devp ? de0 : ce0) + (size_t)cat.x * EMB;
  const float* __restrict__ e1p = (devp ? de1 : ce1) + (size_t)cat.y * EMB;

  // wave-uniform scalar pointers: this head's W slab / bias / attn vector
  const float* Wg = uniform_ptr(devp ? Wd : Wc) + (size_t)g * FEAT * OUTD;
  const float* bg = uniform_ptr(devp ? bd : bc) + g * OUTD;
  const float* ag = uniform_ptr(aW) + g * 2 * OUTD + (devp ? OUTD : 0);

  float acc[OUTD];
#pragma unroll
  for (int o = 0; o < OUTD; ++o) acc[o] = bg[o];

  // ---- cont features 0..55 (full unroll: max scheduling freedom) ----
#pragma unroll
  for (int c = 0; c < 7; ++c) {
    const float2* p = reinterpret_cast<const float2*>(crow + c * 8);
    const float2 a0 = p[0], a1 = p[1], a2 = p[2], a3 = p[3];
    const float xs[8] = {a0.x, a0.y, a1.x, a1.y, a2.x, a2.y, a3.x, a3.y};
#pragma unroll
    for (int k = 0; k < 8; ++k) fma16(acc, xs[k], Wg, c * 8 + k);
  }
  // ---- tail 56..61 ----
  {
    const float2* p = reinterpret_cast<const float2*>(crow + 56);
    const float2 a0 = p[0], a1 = p[1], a2 = p[2];
    const float xs[6] = {a0.x, a0.y, a1.x, a1.y, a2.x, a2.y};
#pragma unroll
    for (int k = 0; k < 6; ++k) fma16(acc, xs[k], Wg, 56 + k);
  }
  // ---- embedding 0: features 62..77 ----
  {
    const float4* p = reinterpret_cast<const float4*>(e0p);
    const float4 a0 = p[0], a1 = p[1], a2 = p[2], a3 = p[3];
    const float xs[16] = {a0.x, a0.y, a0.z, a0.w, a1.x, a1.y, a1.z, a1.w,
                          a2.x, a2.y, a2.z, a2.w, a3.x, a3.y, a3.z, a3.w};
#pragma unroll
    for (int k = 0; k < 16; ++k) fma16(acc, xs[k], Wg, CONTF + k);
  }
  // ---- embedding 1: features 78..93 ----
  {
    const float4* p = reinterpret_cast<const float4*>(e1p);
    const float4 a0 = p[0], a1 = p[1], a2 = p[2], a3 = p[3];
    const float xs[16] = {a0.x, a0.y, a0.z, a0.w, a1.x, a1.y, a1.z, a1.w,
                          a2.x, a2.y, a2.z, a2.w, a3.x, a3.y, a3.z, a3.w};
#pragma unroll
    for (int k = 0; k < 16; ++k) fma16(acc, xs[k], Wg, CONTF + EMB + k);
  }

  // ---- logit: in-lane dot with this head's attn vector ----
  float ev = 0.f;
#pragma unroll
  for (int o = 0; o < OUTD; ++o) ev = fmaf(acc[o], ag[o], ev);

  if (devp) {
    if (valid) {
      float4* hr = reinterpret_cast<float4*>(h_d + (size_t)row * HOUT + g * OUTD);
      hr[0] = make_float4(acc[0], acc[1], acc[2], acc[3]);
      hr[1] = make_float4(acc[4], acc[5], acc[6], acc[7]);
      hr[2] = make_float4(acc[8], acc[9], acc[10], acc[11]);
      hr[3] = make_float4(acc[12], acc[13], acc[14], acc[15]);
      e_d[(size_t)row * NH + g] = ev;
    }
  } else {
    e_c[(size_t)row * NH + g] = ev;
  }
}

// ---------------- K2: attention + fusion-row build ----------------
__global__ __launch_bounds__(256, 4) void k_attn(
    const int* __restrict__ neighbor_idx, const int* __restrict__ device_idx,
    const int* __restrict__ device_cat, const float* __restrict__ device_cont,
    const float* __restrict__ de0, const float* __restrict__ de1,
    const int* __restrict__ combin_idx, const int* __restrict__ combin_cat,
    const float* __restrict__ combin_cont,
    const float* __restrict__ ce0, const float* __restrict__ ce1,
    const float* __restrict__ h_d, const float* __restrict__ e_d,
    const float* __restrict__ e_c, const float* __restrict__ ab,
    const float* __restrict__ W1, const float* __restrict__ b1,
    float* __restrict__ fus) {
  __shared__ __align__(16) float pb[4][NH][68];
  __shared__ __align__(16) int   nb[4][KNBR];
  __shared__ float hb[4][HOUT];
  __shared__ float afb[4][OUTD];

  const int lane = threadIdx.x & 63;
  const int wid  = __builtin_amdgcn_readfirstlane((int)(threadIdx.x >> 6));
  const int b    = blockIdx.x * 4 + wid;

  // ---- phase 1: lane = neighbor k ----
  const int nk = neighbor_idx[(size_t)b * KNBR + lane];
  const float4 ed4 = *reinterpret_cast<const float4*>(e_d + (size_t)nk * NH);
  const float4 ec4 = *reinterpret_cast<const float4*>(e_c + (size_t)b * NH);
  const float4 ab4 = *reinterpret_cast<const float4*>(ab);

  float v0 = ec4.x + ed4.x + ab4.x;
  float v1 = ec4.y + ed4.y + ab4.y;
  float v2 = ec4.z + ed4.z + ab4.z;
  float v3 = ec4.w + ed4.w + ab4.w;
  v0 = v0 > 0.f ? v0 : ALPHA * v0;
  v1 = v1 > 0.f ? v1 : ALPHA * v1;
  v2 = v2 > 0.f ? v2 : ALPHA * v2;
  v3 = v3 > 0.f ? v3 : ALPHA * v3;

  float m0 = v0, m1 = v1, m2 = v2, m3 = v3;
#pragma unroll
  for (int msk = 1; msk < 64; msk <<= 1) {
    m0 = fmaxf(m0, __shfl_xor(m0, msk));
    m1 = fmaxf(m1, __shfl_xor(m1, msk));
    m2 = fmaxf(m2, __shfl_xor(m2, msk));
    m3 = fmaxf(m3, __shfl_xor(m3, msk));
  }
  float p0 = expf(v0 - m0), p1 = expf(v1 - m1), p2 = expf(v2 - m2), p3 = expf(v3 - m3);
  float s0 = p0, s1 = p1, s2 = p2, s3 = p3;
#pragma unroll
  for (int msk = 1; msk < 64; msk <<= 1) {
    s0 += __shfl_xor(s0, msk);
    s1 += __shfl_xor(s1, msk);
    s2 += __shfl_xor(s2, msk);
    s3 += __shfl_xor(s3, msk);
  }
  p0 /= s0; p1 /= s1; p2 /= s2; p3 /= s3;

  pb[wid][0][lane] = p0;
  pb[wid][1][lane] = p1;
  pb[wid][2][lane] = p2;
  pb[wid][3][lane] = p3;
  nb[wid][lane]    = nk;
  __syncthreads();

  // ---- phase 2: lane = (q, c4): q = neighbor quarter, c4 = column quad ----
  // 4x fewer VMEM instrs: one dwordx4 gather per (neighbor, col-quad).
  {
    const int q = lane >> 4, c4 = lane & 15;
    const int hq = c4 >> 2;  // head owning cols 4*c4..4*c4+3
    float ax = 0.f, ay = 0.f, az = 0.f, aw = 0.f;
#pragma unroll
    for (int t = 0; t < 16; ++t) {
      const int n   = nb[wid][q * 16 + t];
      const float p = pb[wid][hq][q * 16 + t];
      const float4 hv =
          *reinterpret_cast<const float4*>(h_d + (size_t)n * HOUT + 4 * c4);
      ax = fmaf(p, hv.x, ax);
      ay = fmaf(p, hv.y, ay);
      az = fmaf(p, hv.z, az);
      aw = fmaf(p, hv.w, aw);
    }
    // reduce over the 4 neighbor-quarters (lanes xor 16, 32)
#pragma unroll
    for (int msk = 16; msk < 64; msk <<= 1) {
      ax += __shfl_xor(ax, msk);
      ay += __shfl_xor(ay, msk);
      az += __shfl_xor(az, msk);
      aw += __shfl_xor(aw, msk);
    }
    if (q == 0) {
      ax = ax > 0.f ? ax : expm1f(ax);
      ay = ay > 0.f ? ay : expm1f(ay);
      az = az > 0.f ? az : expm1f(az);
      aw = aw > 0.f ? aw : expm1f(aw);
      *reinterpret_cast<float4*>(&hb[wid][4 * c4]) = make_float4(ax, ay, az, aw);
    }
  }
  __syncthreads();

  // ---- attn_feats = head_out(64) @ W1(64x16) + b1 ----
  {
    const int j = lane & 15, gg = lane >> 4;
    float part = 0.f;
#pragma unroll
    for (int t = 0; t < 16; ++t)
      part = fmaf(hb[wid][gg * 16 + t], W1[(gg * 16 + t) * OUTD + j], part);
    part += __shfl_xor(part, 16);
    part += __shfl_xor(part, 32);
    if (lane < 16) afb[wid][lane] = part + b1[lane];
  }
  __syncthreads();

  // ---- fusion row [comb 94 | dev 94 | att 16], row-major coalesced ----
  const int ci = combin_idx[b];
  const int cc0 = combin_cat[2 * ci], cc1 = combin_cat[2 * ci + 1];
  const int didx = device_idx[b];
  const int dc0 = device_cat[2 * didx], dc1 = device_cat[2 * didx + 1];
  float* __restrict__ frow = fus + (size_t)b * FUS;
#pragma unroll
  for (int t = 0; t < 4; ++t) {
    const int i = lane + t * 64;
    if (i < FUS) {
      float v;
      if (i < 62)       v = combin_cont[(size_t)ci * CONTF + i];
      else if (i < 78)  v = ce0[(size_t)cc0 * EMB + (i - 62)];
      else if (i < 94)  v = ce1[(size_t)cc1 * EMB + (i - 78)];
      else if (i < 156) v = device_cont[(size_t)didx * CONTF + (i - 94)];
      else if (i < 172) v = de0[(size_t)dc0 * EMB + (i - 156)];
      else if (i < 188) v = de1[(size_t)dc1 * EMB + (i - 172)];
      else              v = afb[wid][i - 188];
      frow[i] = v;
    }
  }
}

// ---------------- K3: MLP (204 -> 64 -> 32 -> 1), 4 rows per wave ----------------
__global__ __launch_bounds__(256) void k_mlp(
    const float* __restrict__ fus,
    const float* __restrict__ W2, const float* __restrict__ b2,
    const float* __restrict__ W3, const float* __restrict__ b3,
    const float* __restrict__ W4, const float* __restrict__ b4,
    float* __restrict__ out) {
  __shared__ __align__(16) float x1w[4][4][64];
  const int lane = threadIdx.x & 63;
  const int wid  = __builtin_amdgcn_readfirstlane((int)(threadIdx.x >> 6));
  const int w    = blockIdx.x * 4 + wid;
  const int r0   = w * 4;

  const float* rp0 = uniform_ptr(fus + (size_t)(r0 + 0) * FUS);
  const float* rp1 = uniform_ptr(fus + (size_t)(r0 + 1) * FUS);
  const float* rp2 = uniform_ptr(fus + (size_t)(r0 + 2) * FUS);
  const float* rp3 = uniform_ptr(fus + (size_t)(r0 + 3) * FUS);

  float acc[4];
  const float bj = b2[lane];
#pragma unroll
  for (int r = 0; r < 4; ++r) acc[r] = bj;

#pragma unroll 1
  for (int c = 0; c < 25; ++c) {
    const int f0 = c * 8;
#pragma unroll
    for (int k = 0; k < 8; ++k) {
      const float wv = W2[(f0 + k) * 64 + lane];
      acc[0] = fmaf(rp0[f0 + k], wv, acc[0]);
      acc[1] = fmaf(rp1[f0 + k], wv, acc[1]);
      acc[2] = fmaf(rp2[f0 + k], wv, acc[2]);
      acc[3] = fmaf(rp3[f0 + k], wv, acc[3]);
    }
  }
#pragma unroll
  for (int k = 0; k < 4; ++k) {
    const float wv = W2[(200 + k) * 64 + lane];
    acc[0] = fmaf(rp0[200 + k], wv, acc[0]);
    acc[1] = fmaf(rp1[200 + k], wv, acc[1]);
    acc[2] = fmaf(rp2[200 + k], wv, acc[2]);
    acc[3] = fmaf(rp3[200 + k], wv, acc[3]);
  }
#pragma unroll
  for (int r = 0; r < 4; ++r) x1w[wid][r][lane] = fmaxf(acc[r], 0.f);

  const int m = lane & 31, rh = lane >> 5;
  float x2[2];
#pragma unroll
  for (int r = 0; r < 2; ++r) x2[r] = b3[m];
#pragma unroll 2
  for (int j4 = 0; j4 < 16; ++j4) {
    const float w30 = W3[(4 * j4 + 0) * 32 + m];
    const float w31 = W3[(4 * j4 + 1) * 32 + m];
    const float w32 = W3[(4 * j4 + 2) * 32 + m];
    const float w33 = W3[(4 * j4 + 3) * 32 + m];
#pragma unroll
    for (int r = 0; r < 2; ++r) {
      const float4 xv = *reinterpret_cast<const float4*>(&x1w[wid][rh * 2 + r][4 * j4]);
      x2[r] = fmaf(xv.x, w30, x2[r]);
      x2[r] = fmaf(xv.y, w31, x2[r]);
      x2[r] = fmaf(xv.z, w32, x2[r]);
      x2[r] = fmaf(xv.w, w33, x2[r]);
    }
  }
  const float w4 = W4[m];
  float part[2];
#pragma unroll
  for (int r = 0; r < 2; ++r) part[r] = fmaxf(x2[r], 0.f) * w4;
#pragma unroll
  for (int msk = 1; msk < 32; msk <<= 1) {
#pragma unroll
    for (int r = 0; r < 2; ++r) part[r] += __shfl_xor(part[r], msk);
  }
  if (m == 0) {
    const float bb = b4[0];
#pragma unroll
    for (int r = 0; r < 2; ++r) {
      const float z = part[r] + bb;
      out[(size_t)(r0 + rh * 2 + r)] = 1.f / (1.f + expf(-z));
    }
  }
}

extern "C" void kernel_launch(void* const* d_in, const int* in_sizes, int n_in,
                              void* d_out, int out_size, void* d_ws, size_t ws_size,
                              hipStream_t stream) {
  const float* combin_cont  = (const float*)d_in[0];
  const int*   combin_cat   = (const int*)d_in[1];
  const float* device_cont  = (const float*)d_in[2];
  const int*   device_cat   = (const int*)d_in[3];
  const int*   combin_idx   = (const int*)d_in[4];
  const int*   device_idx   = (const int*)d_in[5];
  const int*   neighbor_idx = (const int*)d_in[6];
  const float* ce0 = (const float*)d_in[7];
  const float* ce1 = (const float*)d_in[8];
  const float* de0 = (const float*)d_in[9];
  const float* de1 = (const float*)d_in[10];
  const float* Wc  = (const float*)d_in[11];
  const float* bc  = (const float*)d_in[12];
  const float* Wd  = (const float*)d_in[13];
  const float* bd  = (const float*)d_in[14];
  const float* aW  = (const float*)d_in[15];
  const float* ab  = (const float*)d_in[16];
  const float* W1  = (const float*)d_in[17];
  const float* b1  = (const float*)d_in[18];
  const float* W2  = (const float*)d_in[19];
  const float* b2  = (const float*)d_in[20];
  const float* W3  = (const float*)d_in[21];
  const float* b3  = (const float*)d_in[22];
  const float* W4  = (const float*)d_in[23];
  const float* b4  = (const float*)d_in[24];

  float* ws  = (float*)d_ws;
  float* h_d = ws;
  float* e_d = ws + 6400000;
  float* e_c = ws + 6800000;
  float* fus = ws + 6832768;

  k_feat<<<NDEVG + NCOMBG, 256, 0, stream>>>(
      device_cont, device_cat, de0, de1, Wd, bd,
      combin_cont, combin_cat, combin_idx, ce0, ce1, Wc, bc, aW,
      h_d, e_d, e_c);
  k_attn<<<2048, 256, 0, stream>>>(
      neighbor_idx, device_idx, device_cat, device_cont, de0, de1,
      combin_idx, combin_cat, combin_cont, ce0, ce1,
      h_d, e_d, e_c, ab, W1, b1, fus);
  k_mlp<<<512, 256, 0, stream>>>(fus, W2, b2, W3, b3, W4, b4, (float*)d_out);
}

// Round 6
// 186.054 us; speedup vs baseline: 1.1081x; 1.0269x over previous
//
#include <hip/hip_runtime.h>
#include <cmath>

#define NDEV   100000
#define NBATCH 8192
#define CONTF  62
#define EMB    16
#define FEAT   94      // 62 + 16 + 16
#define KNBR   64
#define NH     4
#define OUTD   16
#define HOUT   64      // NH*OUTD
#define FUS    204     // 94 + 94 + 16
#define ALPHA  0.2f

#define NDEVG  1563    // ceil(100000/64) row-groups
#define NCOMBG 128     // 8192/64 row-groups

typedef unsigned short ushortT;
typedef ushortT ushort8v __attribute__((ext_vector_type(8)));

// ---------------- workspace layout (floats) ----------------
// h_bf : NDEV*64 bf16 = 3,200,000 float-slots @ 0   (12.8 MB)
// e_d  : NDEV*4       =   400,000 @ 3,200,000
// e_c  : NBATCH*4     =    32,768 @ 3,600,000
// fus  : NBATCH*204   = 1,671,168 @ 3,632,768   (row-major [b][204])

template <typename T>
__device__ __forceinline__ const T* uniform_ptr(const T* p) {
  uint64_t v = (uint64_t)(uintptr_t)p;
  uint32_t lo = __builtin_amdgcn_readfirstlane((uint32_t)v);
  uint32_t hi = __builtin_amdgcn_readfirstlane((uint32_t)(v >> 32));
  return (const T*)(uintptr_t)(((uint64_t)hi << 32) | lo);
}

__device__ __forceinline__ float bf2f(ushortT u) {
  return __uint_as_float(((unsigned int)u) << 16);
}
__device__ __forceinline__ ushortT f2bf(float f) {
  unsigned int i = __float_as_uint(f);
  unsigned int r = i + 0x7FFFu + ((i >> 16) & 1u);  // round-to-nearest-even
  return (ushortT)(r >> 16);
}

// 16 FMAs for one feature; Wg = this head's [f][16] slab (uniform address ->
// s_load_dwordx16 feed on the scalar pipe).
__device__ __forceinline__ void fma16(float acc[OUTD], float x,
                                      const float* __restrict__ Wg, int f) {
  const float4* wr = reinterpret_cast<const float4*>(Wg + f * OUTD);
  const float4 w0 = wr[0], w1 = wr[1], w2 = wr[2], w3 = wr[3];
  acc[0]  = fmaf(x, w0.x, acc[0]);  acc[1]  = fmaf(x, w0.y, acc[1]);
  acc[2]  = fmaf(x, w0.z, acc[2]);  acc[3]  = fmaf(x, w0.w, acc[3]);
  acc[4]  = fmaf(x, w1.x, acc[4]);  acc[5]  = fmaf(x, w1.y, acc[5]);
  acc[6]  = fmaf(x, w1.z, acc[6]);  acc[7]  = fmaf(x, w1.w, acc[7]);
  acc[8]  = fmaf(x, w2.x, acc[8]);  acc[9]  = fmaf(x, w2.y, acc[9]);
  acc[10] = fmaf(x, w2.z, acc[10]); acc[11] = fmaf(x, w2.w, acc[11]);
  acc[12] = fmaf(x, w3.x, acc[12]); acc[13] = fmaf(x, w3.y, acc[13]);
  acc[14] = fmaf(x, w3.z, acc[14]); acc[15] = fmaf(x, w3.w, acc[15]);
}

// ---------------- K1: X[row,94] @ W[94,64], wave = (64 rows, 1 head) ---------
__global__ __launch_bounds__(256, 4) void k_feat(
    const float* __restrict__ device_cont, const int* __restrict__ device_cat,
    const float* __restrict__ de0, const float* __restrict__ de1,
    const float* __restrict__ Wd, const float* __restrict__ bd,
    const float* __restrict__ combin_cont, const int* __restrict__ combin_cat,
    const int* __restrict__ combin_idx,
    const float* __restrict__ ce0, const float* __restrict__ ce1,
    const float* __restrict__ Wc, const float* __restrict__ bc,
    const float* __restrict__ aW,
    ushortT* __restrict__ h_bf, float* __restrict__ e_d, float* __restrict__ e_c) {
  const int lane = threadIdx.x & 63;
  const int g = __builtin_amdgcn_readfirstlane((int)(threadIdx.x >> 6));  // head
  const int blk = blockIdx.x;
  const bool devp = blk < NDEVG;

  const int row = (devp ? blk : blk - NDEVG) * 64 + lane;
  const bool valid = devp ? (row < NDEV) : true;
  const int rr = valid ? row : NDEV - 1;

  const int src = devp ? rr : combin_idx[rr];
  const int2 cat = reinterpret_cast<const int2*>(devp ? device_cat : combin_cat)[src];
  const float* __restrict__ crow =
      (devp ? device_cont : combin_cont) + (size_t)src * CONTF;
  const float* __restrict__ e0p = (devp ? de0 : ce0) + (size_t)cat.x * EMB;
  const float* __restrict__ e1p = (devp ? de1 : ce1) + (size_t)cat.y * EMB;

  const float* Wg = uniform_ptr(devp ? Wd : Wc) + (size_t)g * FEAT * OUTD;
  const float* bg = uniform_ptr(devp ? bd : bc) + g * OUTD;
  const float* ag = uniform_ptr(aW) + g * 2 * OUTD + (devp ? OUTD : 0);

  float acc[OUTD];
#pragma unroll
  for (int o = 0; o < OUTD; ++o) acc[o] = bg[o];

#pragma unroll
  for (int c = 0; c < 7; ++c) {
    const float2* p = reinterpret_cast<const float2*>(crow + c * 8);
    const float2 a0 = p[0], a1 = p[1], a2 = p[2], a3 = p[3];
    const float xs[8] = {a0.x, a0.y, a1.x, a1.y, a2.x, a2.y, a3.x, a3.y};
#pragma unroll
    for (int k = 0; k < 8; ++k) fma16(acc, xs[k], Wg, c * 8 + k);
  }
  {
    const float2* p = reinterpret_cast<const float2*>(crow + 56);
    const float2 a0 = p[0], a1 = p[1], a2 = p[2];
    const float xs[6] = {a0.x, a0.y, a1.x, a1.y, a2.x, a2.y};
#pragma unroll
    for (int k = 0; k < 6; ++k) fma16(acc, xs[k], Wg, 56 + k);
  }
  {
    const float4* p = reinterpret_cast<const float4*>(e0p);
    const float4 a0 = p[0], a1 = p[1], a2 = p[2], a3 = p[3];
    const float xs[16] = {a0.x, a0.y, a0.z, a0.w, a1.x, a1.y, a1.z, a1.w,
                          a2.x, a2.y, a2.z, a2.w, a3.x, a3.y, a3.z, a3.w};
#pragma unroll
    for (int k = 0; k < 16; ++k) fma16(acc, xs[k], Wg, CONTF + k);
  }
  {
    const float4* p = reinterpret_cast<const float4*>(e1p);
    const float4 a0 = p[0], a1 = p[1], a2 = p[2], a3 = p[3];
    const float xs[16] = {a0.x, a0.y, a0.z, a0.w, a1.x, a1.y, a1.z, a1.w,
                          a2.x, a2.y, a2.z, a2.w, a3.x, a3.y, a3.z, a3.w};
#pragma unroll
    for (int k = 0; k < 16; ++k) fma16(acc, xs[k], Wg, CONTF + EMB + k);
  }

  // logit from fp32 acc (so softmax weights stay near-exact)
  float ev = 0.f;
#pragma unroll
  for (int o = 0; o < OUTD; ++o) ev = fmaf(acc[o], ag[o], ev);

  if (devp) {
    if (valid) {
      ushort8v v0, v1;
#pragma unroll
      for (int o = 0; o < 8; ++o) { v0[o] = f2bf(acc[o]); v1[o] = f2bf(acc[8 + o]); }
      ushort8v* dst = reinterpret_cast<ushort8v*>(h_bf + (size_t)row * HOUT + g * OUTD);
      dst[0] = v0;
      dst[1] = v1;
      e_d[(size_t)row * NH + g] = ev;
    }
  } else {
    e_c[(size_t)row * NH + g] = ev;
  }
}

// ---------------- K2: attention + fusion-row build ----------------
__global__ __launch_bounds__(256, 4) void k_attn(
    const int* __restrict__ neighbor_idx, const int* __restrict__ device_idx,
    const int* __restrict__ device_cat, const float* __restrict__ device_cont,
    const float* __restrict__ de0, const float* __restrict__ de1,
    const int* __restrict__ combin_idx, const int* __restrict__ combin_cat,
    const float* __restrict__ combin_cont,
    const float* __restrict__ ce0, const float* __restrict__ ce1,
    const ushortT* __restrict__ h_bf, const float* __restrict__ e_d,
    const float* __restrict__ e_c, const float* __restrict__ ab,
    const float* __restrict__ W1, const float* __restrict__ b1,
    float* __restrict__ fus) {
  __shared__ __align__(16) float pb[4][NH][68];
  __shared__ __align__(16) int   nb[4][KNBR];
  __shared__ float hb[4][HOUT];
  __shared__ float afb[4][OUTD];

  const int lane = threadIdx.x & 63;
  const int wid  = __builtin_amdgcn_readfirstlane((int)(threadIdx.x >> 6));
  const int b    = blockIdx.x * 4 + wid;

  // ---- phase 1: lane = neighbor k ----
  const int nk = neighbor_idx[(size_t)b * KNBR + lane];
  const float4 ed4 = *reinterpret_cast<const float4*>(e_d + (size_t)nk * NH);
  const float4 ec4 = *reinterpret_cast<const float4*>(e_c + (size_t)b * NH);
  const float4 ab4 = *reinterpret_cast<const float4*>(ab);

  float v0 = ec4.x + ed4.x + ab4.x;
  float v1 = ec4.y + ed4.y + ab4.y;
  float v2 = ec4.z + ed4.z + ab4.z;
  float v3 = ec4.w + ed4.w + ab4.w;
  v0 = v0 > 0.f ? v0 : ALPHA * v0;
  v1 = v1 > 0.f ? v1 : ALPHA * v1;
  v2 = v2 > 0.f ? v2 : ALPHA * v2;
  v3 = v3 > 0.f ? v3 : ALPHA * v3;

  float m0 = v0, m1 = v1, m2 = v2, m3 = v3;
#pragma unroll
  for (int msk = 1; msk < 64; msk <<= 1) {
    m0 = fmaxf(m0, __shfl_xor(m0, msk));
    m1 = fmaxf(m1, __shfl_xor(m1, msk));
    m2 = fmaxf(m2, __shfl_xor(m2, msk));
    m3 = fmaxf(m3, __shfl_xor(m3, msk));
  }
  float p0 = expf(v0 - m0), p1 = expf(v1 - m1), p2 = expf(v2 - m2), p3 = expf(v3 - m3);
  float s0 = p0, s1 = p1, s2 = p2, s3 = p3;
#pragma unroll
  for (int msk = 1; msk < 64; msk <<= 1) {
    s0 += __shfl_xor(s0, msk);
    s1 += __shfl_xor(s1, msk);
    s2 += __shfl_xor(s2, msk);
    s3 += __shfl_xor(s3, msk);
  }
  p0 /= s0; p1 /= s1; p2 /= s2; p3 /= s3;

  pb[wid][0][lane] = p0;
  pb[wid][1][lane] = p1;
  pb[wid][2][lane] = p2;
  pb[wid][3][lane] = p3;
  nb[wid][lane]    = nk;
  __syncthreads();

  // ---- phase 2: lane = (q, c8): q = 8-neighbor group, c8 = column oct ----
  // bf16 gather: one 16B load = 8 cols; half the instrs AND bytes of fp32.
  {
    const int q = lane >> 3, c8 = lane & 7;
    const int hq = c8 >> 1;  // head owning cols 8*c8..8*c8+7
    float a[8];
#pragma unroll
    for (int i = 0; i < 8; ++i) a[i] = 0.f;
#pragma unroll
    for (int t = 0; t < 8; ++t) {
      const int k   = q * 8 + t;
      const int n   = nb[wid][k];
      const float p = pb[wid][hq][k];
      const ushort8v hv =
          *reinterpret_cast<const ushort8v*>(h_bf + (size_t)n * HOUT + c8 * 8);
#pragma unroll
      for (int i = 0; i < 8; ++i) a[i] = fmaf(p, bf2f(hv[i]), a[i]);
    }
    // reduce over the 8 neighbor-groups (lanes xor 8,16,32)
#pragma unroll
    for (int msk = 8; msk < 64; msk <<= 1) {
#pragma unroll
      for (int i = 0; i < 8; ++i) a[i] += __shfl_xor(a[i], msk);
    }
    if (q == 0) {
#pragma unroll
      for (int i = 0; i < 8; ++i) a[i] = a[i] > 0.f ? a[i] : expm1f(a[i]);  // elu
      float4* hp = reinterpret_cast<float4*>(&hb[wid][c8 * 8]);
      hp[0] = make_float4(a[0], a[1], a[2], a[3]);
      hp[1] = make_float4(a[4], a[5], a[6], a[7]);
    }
  }
  __syncthreads();

  // ---- attn_feats = head_out(64) @ W1(64x16) + b1 ----
  {
    const int j = lane & 15, gg = lane >> 4;
    float part = 0.f;
#pragma unroll
    for (int t = 0; t < 16; ++t)
      part = fmaf(hb[wid][gg * 16 + t], W1[(gg * 16 + t) * OUTD + j], part);
    part += __shfl_xor(part, 16);
    part += __shfl_xor(part, 32);
    if (lane < 16) afb[wid][lane] = part + b1[lane];
  }
  __syncthreads();

  // ---- fusion row [comb 94 | dev 94 | att 16], row-major coalesced ----
  const int ci = combin_idx[b];
  const int cc0 = combin_cat[2 * ci], cc1 = combin_cat[2 * ci + 1];
  const int didx = device_idx[b];
  const int dc0 = device_cat[2 * didx], dc1 = device_cat[2 * didx + 1];
  float* __restrict__ frow = fus + (size_t)b * FUS;
#pragma unroll
  for (int t = 0; t < 4; ++t) {
    const int i = lane + t * 64;
    if (i < FUS) {
      float v;
      if (i < 62)       v = combin_cont[(size_t)ci * CONTF + i];
      else if (i < 78)  v = ce0[(size_t)cc0 * EMB + (i - 62)];
      else if (i < 94)  v = ce1[(size_t)cc1 * EMB + (i - 78)];
      else if (i < 156) v = device_cont[(size_t)didx * CONTF + (i - 94)];
      else if (i < 172) v = de0[(size_t)dc0 * EMB + (i - 156)];
      else if (i < 188) v = de1[(size_t)dc1 * EMB + (i - 172)];
      else              v = afb[wid][i - 188];
      frow[i] = v;
    }
  }
}

// ---------------- K3: MLP (204 -> 64 -> 32 -> 1), 8 rows/block, f-split -----
__global__ __launch_bounds__(256) void k_mlp(
    const float* __restrict__ fus,
    const float* __restrict__ W2, const float* __restrict__ b2,
    const float* __restrict__ W3, const float* __restrict__ b3,
    const float* __restrict__ W4, const float* __restrict__ b4,
    float* __restrict__ out) {
  __shared__ __align__(16) float part[4][4][64];  // [wave][r][col]
  __shared__ __align__(16) float x1s[2][4][64];   // [pair][r][col]
  const int tid  = threadIdx.x;
  const int lane = tid & 63;
  const int wid  = __builtin_amdgcn_readfirstlane((int)(tid >> 6));
  const int pair = wid >> 1, half = wid & 1;
  const int r0   = blockIdx.x * 8 + pair * 4;  // this wave-pair's 4 rows
  const int f0   = half * 102;                 // feature half

  const float* rp0 = uniform_ptr(fus + (size_t)(r0 + 0) * FUS + f0);
  const float* rp1 = uniform_ptr(fus + (size_t)(r0 + 1) * FUS + f0);
  const float* rp2 = uniform_ptr(fus + (size_t)(r0 + 2) * FUS + f0);
  const float* rp3 = uniform_ptr(fus + (size_t)(r0 + 3) * FUS + f0);

  float acc[4];
  const float bj = half ? 0.f : b2[lane];
#pragma unroll
  for (int r = 0; r < 4; ++r) acc[r] = bj;

#pragma unroll 1
  for (int c = 0; c < 17; ++c) {  // 17*6 = 102
#pragma unroll
    for (int k = 0; k < 6; ++k) {
      const int f = c * 6 + k;
      const float wv = W2[(f0 + f) * 64 + lane];
      acc[0] = fmaf(rp0[f], wv, acc[0]);
      acc[1] = fmaf(rp1[f], wv, acc[1]);
      acc[2] = fmaf(rp2[f], wv, acc[2]);
      acc[3] = fmaf(rp3[f], wv, acc[3]);
    }
  }
#pragma unroll
  for (int r = 0; r < 4; ++r) part[wid][r][lane] = acc[r];
  __syncthreads();

  if (half == 0) {
#pragma unroll
    for (int r = 0; r < 4; ++r)
      x1s[pair][r][lane] = fmaxf(part[wid][r][lane] + part[wid + 1][r][lane], 0.f);
  }
  __syncthreads();

  // layer 2: 256 threads = 8 rows x 32 cols
  const int row = tid >> 5, m = tid & 31;
  const int pr = row >> 2, rr = row & 3;
  float x2 = b3[m];
#pragma unroll 2
  for (int j4 = 0; j4 < 16; ++j4) {
    const float4 xv = *reinterpret_cast<const float4*>(&x1s[pr][rr][4 * j4]);
    x2 = fmaf(xv.x, W3[(4 * j4 + 0) * 32 + m], x2);
    x2 = fmaf(xv.y, W3[(4 * j4 + 1) * 32 + m], x2);
    x2 = fmaf(xv.z, W3[(4 * j4 + 2) * 32 + m], x2);
    x2 = fmaf(xv.w, W3[(4 * j4 + 3) * 32 + m], x2);
  }
  // layer 3 + sigmoid: reduce over the 32 cols of this row
  float p3r = fmaxf(x2, 0.f) * W4[m];
#pragma unroll
  for (int msk = 1; msk < 32; msk <<= 1) p3r += __shfl_xor(p3r, msk);
  if (m == 0) {
    const float z = p3r + b4[0];
    out[(size_t)(blockIdx.x * 8 + row)] = 1.f / (1.f + expf(-z));
  }
}

extern "C" void kernel_launch(void* const* d_in, const int* in_sizes, int n_in,
                              void* d_out, int out_size, void* d_ws, size_t ws_size,
                              hipStream_t stream) {
  const float* combin_cont  = (const float*)d_in[0];
  const int*   combin_cat   = (const int*)d_in[1];
  const float* device_cont  = (const float*)d_in[2];
  const int*   device_cat   = (const int*)d_in[3];
  const int*   combin_idx   = (const int*)d_in[4];
  const int*   device_idx   = (const int*)d_in[5];
  const int*   neighbor_idx = (const int*)d_in[6];
  const float* ce0 = (const float*)d_in[7];
  const float* ce1 = (const float*)d_in[8];
  const float* de0 = (const float*)d_in[9];
  const float* de1 = (const float*)d_in[10];
  const float* Wc  = (const float*)d_in[11];
  const float* bc  = (const float*)d_in[12];
  const float* Wd  = (const float*)d_in[13];
  const float* bd  = (const float*)d_in[14];
  const float* aW  = (const float*)d_in[15];
  const float* ab  = (const float*)d_in[16];
  const float* W1  = (const float*)d_in[17];
  const float* b1  = (const float*)d_in[18];
  const float* W2  = (const float*)d_in[19];
  const float* b2  = (const float*)d_in[20];
  const float* W3  = (const float*)d_in[21];
  const float* b3  = (const float*)d_in[22];
  const float* W4  = (const float*)d_in[23];
  const float* b4  = (const float*)d_in[24];

  float* ws  = (float*)d_ws;
  ushortT* h_bf = (ushortT*)ws;
  float* e_d = ws + 3200000;
  float* e_c = ws + 3600000;
  float* fus = ws + 3632768;

  k_feat<<<NDEVG + NCOMBG, 256, 0, stream>>>(
      device_cont, device_cat, de0, de1, Wd, bd,
      combin_cont, combin_cat, combin_idx, ce0, ce1, Wc, bc, aW,
      h_bf, e_d, e_c);
  k_attn<<<2048, 256, 0, stream>>>(
      neighbor_idx, device_idx, device_cat, device_cont, de0, de1,
      combin_idx, combin_cat, combin_cont, ce0, ce1,
      h_bf, e_d, e_c, ab, W1, b1, fus);
  k_mlp<<<1024, 256, 0, stream>>>(fus, W2, b2, W3, b3, W4, b4, (float*)d_out);
}